// Round 8
// baseline (1535.501 us; speedup 1.0000x reference)
//
#include <hip/hip_runtime.h>
#include <math.h>

// ---- problem constants ----
#define V_   256
#define S_   1024
#define D_   768
#define H_   12
#define L_   4
#define DS_  3
#define B_   4
#define DH_  64        // D_/H_
#define BS_  (B_*S_)   // 4096
#define D3_  (3*D_)    // 2304
#define D4_  (4*D_)    // 3072
#define BSV_ (BS_*V_)  // 1048576

typedef __attribute__((ext_vector_type(8))) short short8;
typedef __attribute__((ext_vector_type(4))) float f32x4;

__device__ __forceinline__ ushort f2bf(float f) {
    unsigned u = __float_as_uint(f);
    u = (u + 0x7fffu + ((u >> 16) & 1u)) >> 16;
    return (ushort)u;
}

// ---------------------------------------------------------------
// block-wide reductions (256 threads = 4 waves of 64)
// ---------------------------------------------------------------
__device__ __forceinline__ float block_sum(float v, float* red) {
    #pragma unroll
    for (int m = 32; m > 0; m >>= 1) v += __shfl_xor(v, m, 64);
    int wid = threadIdx.x >> 6;
    __syncthreads();
    if ((threadIdx.x & 63) == 0) red[wid] = v;
    __syncthreads();
    return red[0] + red[1] + red[2] + red[3];
}

__device__ __forceinline__ float block_max(float v, float* red) {
    #pragma unroll
    for (int m = 32; m > 0; m >>= 1) v = fmaxf(v, __shfl_xor(v, m, 64));
    int wid = threadIdx.x >> 6;
    __syncthreads();
    if ((threadIdx.x & 63) == 0) red[wid] = v;
    __syncthreads();
    return fmaxf(fmaxf(red[0], red[1]), fmaxf(red[2], red[3]));
}

// ---------------------------------------------------------------
__global__ void zero_kernel(float* acc) {
    if (threadIdx.x < 8) acc[threadIdx.x] = 0.0f;
}

// ---------------------------------------------------------------
// embedding: x = tok_emb[idx] + pos_emb[t] + sp @ pproj ; stash sp
// ---------------------------------------------------------------
__global__ __launch_bounds__(256) void embed_kernel(
    const int* __restrict__ idx, const float* __restrict__ tok_emb,
    const float* __restrict__ pos_emb, const float* __restrict__ tok_pos,
    const float* __restrict__ pproj, float* __restrict__ x, float* __restrict__ sp)
{
    int r = blockIdx.x;                 // b*S + t
    int t = r & (S_ - 1);
    int id = idx[r];
    float s0 = tok_pos[id*3+0], s1 = tok_pos[id*3+1], s2 = tok_pos[id*3+2];
    if (threadIdx.x == 0) { sp[r*3+0] = s0; sp[r*3+1] = s1; sp[r*3+2] = s2; }
    for (int d = threadIdx.x; d < D_; d += 256) {
        x[(size_t)r*D_ + d] = tok_emb[(size_t)id*D_ + d] + pos_emb[(size_t)t*D_ + d]
                            + s0*pproj[d] + s1*pproj[D_+d] + s2*pproj[2*D_+d];
    }
}

// ---------------------------------------------------------------
// layernorm: OUT=0 -> f32, OUT=1 -> bf16
// ---------------------------------------------------------------
template<int OUT>
__global__ __launch_bounds__(256) void ln_kernel(
    const float* __restrict__ in, const float* __restrict__ g,
    const float* __restrict__ b, void* __restrict__ outv)
{
    __shared__ float red[4];
    int r = blockIdx.x, tid = threadIdx.x;
    const float* p = in + (size_t)r*D_;
    float v0 = p[tid], v1 = p[tid+256], v2 = p[tid+512];
    float s = block_sum(v0+v1+v2, red);
    float mean = s * (1.0f/768.0f);
    float d0 = v0-mean, d1 = v1-mean, d2 = v2-mean;
    float var = block_sum(d0*d0+d1*d1+d2*d2, red) * (1.0f/768.0f);
    float inv = rsqrtf(var + 1e-5f);
    float o0 = d0*inv*g[tid    ] + b[tid    ];
    float o1 = d1*inv*g[tid+256] + b[tid+256];
    float o2 = d2*inv*g[tid+512] + b[tid+512];
    if (OUT == 0) {
        float* o = (float*)outv + (size_t)r*D_;
        o[tid] = o0; o[tid+256] = o1; o[tid+512] = o2;
    } else {
        ushort* o = (ushort*)outv + (size_t)r*D_;
        o[tid] = f2bf(o0); o[tid+256] = f2bf(o1); o[tid+512] = f2bf(o2);
    }
}

// ---------------------------------------------------------------
// all four per-layer weight transposes in one dispatch.
// f32 W[K][N] -> bf16 Wt[N][K], 32x32 tiles.
// bid ranges: wq 1728 | wp 576 | w1 2304 | w2 2304  (total 6912)
// ---------------------------------------------------------------
__global__ __launch_bounds__(256) void transpose_all_kernel(
    const float* __restrict__ Wq, const float* __restrict__ Wp,
    const float* __restrict__ W1, const float* __restrict__ W2,
    ushort* __restrict__ wqT, ushort* __restrict__ wpT,
    ushort* __restrict__ w1T, ushort* __restrict__ w2T)
{
    int bid = blockIdx.x;
    const float* W; ushort* Wt; int K, N, nx;
    if (bid < 1728)      { W = Wq; Wt = wqT; K = 768;  N = 2304; nx = 72; }
    else if (bid < 2304) { bid -= 1728; W = Wp; Wt = wpT; K = 768;  N = 768;  nx = 24; }
    else if (bid < 4608) { bid -= 2304; W = W1; Wt = w1T; K = 768;  N = 3072; nx = 96; }
    else                 { bid -= 4608; W = W2; Wt = w2T; K = 3072; N = 768;  nx = 24; }

    __shared__ float t[32][33];
    int n0 = (bid % nx) * 32, k0 = (bid / nx) * 32;
    int tx = threadIdx.x & 31, ty = threadIdx.x >> 5;   // ty 0..7
    #pragma unroll
    for (int r = 0; r < 32; r += 8)
        t[ty+r][tx] = W[(size_t)(k0+ty+r)*N + n0 + tx];
    __syncthreads();
    #pragma unroll
    for (int r = 0; r < 32; r += 8)
        Wt[(size_t)(n0+ty+r)*K + k0 + tx] = f2bf(t[tx][ty+r]);
}

// ---------------------------------------------------------------
// bf16 MFMA GEMM: C[M,N] = A[M,K] @ Bt[N,K]^T  (both operands [row][K] bf16)
// 128x128 tile, BK=32, 4 waves, wave = 64x64 via 4x4 of 16x16x32 MFMA.
// EPI: 0 = f32 C ; 1 = f32 C=acc+res ; 2 = bf16 C=gelu(acc+bias) ;
//      3 = f32 C=acc+bias+res ; 4 = qkv split (q,k bf16 -> Cout[row][1536],
//          v transposed bf16 -> aux[(b*768+rel)][t])
// ---------------------------------------------------------------
template<int EPI>
__global__ __launch_bounds__(256) void gemm_bf16_kernel(
    const ushort* __restrict__ A, const ushort* __restrict__ Bt,
    const float* __restrict__ bias, const float* __restrict__ res,
    void* __restrict__ Cout, void* __restrict__ aux, int M, int N, int K)
{
    __shared__ ushort As[128*32];
    __shared__ ushort Bs[128*32];
    int tid = threadIdx.x;
    int w = tid >> 6, l = tid & 63;
    int bm = blockIdx.y * 128, bn = blockIdx.x * 128;
    int wm = (w >> 1) * 64, wn = (w & 1) * 64;

    f32x4 acc[4][4];
    #pragma unroll
    for (int i = 0; i < 4; ++i)
        #pragma unroll
        for (int j = 0; j < 4; ++j) { acc[i][j][0]=0.f; acc[i][j][1]=0.f; acc[i][j][2]=0.f; acc[i][j][3]=0.f; }

    int rl = l >> 2;                          // 0..15
    int sg = (l & 3) ^ ((rl >> 1) & 3);       // pre-swizzled src k-group
    const ushort* ap0 = A  + (size_t)(bm + (w*2  )*16 + rl)*K + sg*8;
    const ushort* ap1 = A  + (size_t)(bm + (w*2+1)*16 + rl)*K + sg*8;
    const ushort* bp0 = Bt + (size_t)(bn + (w*2  )*16 + rl)*K + sg*8;
    const ushort* bp1 = Bt + (size_t)(bn + (w*2+1)*16 + rl)*K + sg*8;
    ushort* al0 = &As[(w*2  )*512];
    ushort* al1 = &As[(w*2+1)*512];
    ushort* bl0 = &Bs[(w*2  )*512];
    ushort* bl1 = &Bs[(w*2+1)*512];

    #define STAGE(K0) do { \
        __builtin_amdgcn_global_load_lds((const __attribute__((address_space(1))) void*)(ap0 + (K0)), (__attribute__((address_space(3))) void*)al0, 16, 0, 0); \
        __builtin_amdgcn_global_load_lds((const __attribute__((address_space(1))) void*)(ap1 + (K0)), (__attribute__((address_space(3))) void*)al1, 16, 0, 0); \
        __builtin_amdgcn_global_load_lds((const __attribute__((address_space(1))) void*)(bp0 + (K0)), (__attribute__((address_space(3))) void*)bl0, 16, 0, 0); \
        __builtin_amdgcn_global_load_lds((const __attribute__((address_space(1))) void*)(bp1 + (K0)), (__attribute__((address_space(3))) void*)bl1, 16, 0, 0); \
    } while (0)

    int lq = l & 15, lg = l >> 4;
    STAGE(0);

    for (int k0 = 0; k0 < K; k0 += 32) {
        __syncthreads();
        short8 af[4], bfv[4];
        #pragma unroll
        for (int mi = 0; mi < 4; ++mi) {
            int r = wm + mi*16 + lq;
            int ks = lg ^ ((r >> 1) & 3);
            af[mi] = *(const short8*)&As[r*32 + ks*8];
        }
        #pragma unroll
        for (int ni = 0; ni < 4; ++ni) {
            int r = wn + ni*16 + lq;
            int ks = lg ^ ((r >> 1) & 3);
            bfv[ni] = *(const short8*)&Bs[r*32 + ks*8];
        }
        #pragma unroll
        for (int mi = 0; mi < 4; ++mi)
            #pragma unroll
            for (int ni = 0; ni < 4; ++ni)
                acc[mi][ni] = __builtin_amdgcn_mfma_f32_16x16x32_bf16(af[mi], bfv[ni], acc[mi][ni], 0, 0, 0);
        __syncthreads();
        if (k0 + 32 < K) STAGE(k0 + 32);
    }
    #undef STAGE

    // epilogue: C/D map col=lane&15, row=(lane>>4)*4+q
    int lr = (l >> 4) * 4;
    #pragma unroll
    for (int mi = 0; mi < 4; ++mi) {
        #pragma unroll
        for (int ni = 0; ni < 4; ++ni) {
            int col = bn + wn + ni*16 + lq;
            int row = bm + wm + mi*16 + lr;
            if (EPI == 4) {
                if (col < 1536) {
                    #pragma unroll
                    for (int q = 0; q < 4; ++q)
                        ((ushort*)Cout)[(size_t)(row+q)*1536 + col] = f2bf(acc[mi][ni][q]);
                } else {
                    int bb = row >> 10, t0 = row & 1023;
                    ushort4 pv = make_ushort4(f2bf(acc[mi][ni][0]), f2bf(acc[mi][ni][1]),
                                              f2bf(acc[mi][ni][2]), f2bf(acc[mi][ni][3]));
                    *(ushort4*)&((ushort*)aux)[((size_t)(bb*768) + (col-1536))*1024 + t0] = pv;
                }
            } else {
                #pragma unroll
                for (int q = 0; q < 4; ++q) {
                    size_t o = (size_t)(row + q)*N + col;
                    float v = acc[mi][ni][q];
                    if (EPI == 0) {
                        ((float*)Cout)[o] = v;
                    } else if (EPI == 1) {
                        ((float*)Cout)[o] = v + res[o];
                    } else if (EPI == 2) {
                        float t = v + bias[col];
                        ((ushort*)Cout)[o] = f2bf(0.5f*t*(1.0f + erff(t*0.70710678118f)));
                    } else {
                        ((float*)Cout)[o] = v + bias[col] + res[o];
                    }
                }
            }
        }
    }
}

// ---------------------------------------------------------------
// f32 GEMM (kept for lm_head)  C = A[M,K] @ B^T (B as [N,K])
// ---------------------------------------------------------------
template<int EPI, bool BT>
__global__ __launch_bounds__(256) void gemm_kernel(
    const float* __restrict__ A, const float* __restrict__ Bm,
    const float* __restrict__ bias, const float* __restrict__ res,
    float* __restrict__ C, int M, int N, int K)
{
    __shared__ float As[16][68];
    __shared__ float Bs[16][68];
    int tid = threadIdx.x;
    int tx = tid & 15, ty = tid >> 4;
    int bn = blockIdx.x * 64, bm = blockIdx.y * 64;
    float acc[4][4] = {};

    int arow = tid >> 2;
    int akc  = (tid & 3) * 4;
    int kb   = tid >> 4;
    int nb   = (tid & 15) * 4;

    for (int k0 = 0; k0 < K; k0 += 16) {
        float4 av = *(const float4*)&A[(size_t)(bm+arow)*K + k0 + akc];
        As[akc+0][arow] = av.x; As[akc+1][arow] = av.y;
        As[akc+2][arow] = av.z; As[akc+3][arow] = av.w;
        if (!BT) {
            float4 bv = *(const float4*)&Bm[(size_t)(k0+kb)*N + bn + nb];
            *(float4*)&Bs[kb][nb] = bv;
        } else {
            float4 bv = *(const float4*)&Bm[(size_t)(bn+arow)*K + k0 + akc];
            Bs[akc+0][arow] = bv.x; Bs[akc+1][arow] = bv.y;
            Bs[akc+2][arow] = bv.z; Bs[akc+3][arow] = bv.w;
        }
        __syncthreads();
        #pragma unroll
        for (int kk = 0; kk < 16; ++kk) {
            float4 a = *(const float4*)&As[kk][ty*4];
            float4 b = *(const float4*)&Bs[kk][tx*4];
            acc[0][0] += a.x*b.x; acc[0][1] += a.x*b.y; acc[0][2] += a.x*b.z; acc[0][3] += a.x*b.w;
            acc[1][0] += a.y*b.x; acc[1][1] += a.y*b.y; acc[1][2] += a.y*b.z; acc[1][3] += a.y*b.w;
            acc[2][0] += a.z*b.x; acc[2][1] += a.z*b.y; acc[2][2] += a.z*b.z; acc[2][3] += a.z*b.w;
            acc[3][0] += a.w*b.x; acc[3][1] += a.w*b.y; acc[3][2] += a.w*b.z; acc[3][3] += a.w*b.w;
        }
        __syncthreads();
    }

    int row0 = bm + ty*4, col0 = bn + tx*4;
    #pragma unroll
    for (int mm = 0; mm < 4; ++mm) {
        int r = row0 + mm;
        float4 vv = make_float4(acc[mm][0], acc[mm][1], acc[mm][2], acc[mm][3]);
        if (EPI == 1) {
            float4 rr = *(const float4*)&res[(size_t)r*N + col0];
            vv.x += rr.x; vv.y += rr.y; vv.z += rr.z; vv.w += rr.w;
        }
        *(float4*)&C[(size_t)r*N + col0] = vv;
    }
}

// ---------------------------------------------------------------
// MFMA flash attention, double-buffered K/V, 1 barrier per tile,
// deferred Z/Sde/Sws stats (per-lane partials, one final reduce).
// block = 64 q-rows of one (b,h); 4 waves; KV-tile 64.
// LDS tiles [64][64] bf16, 16B-slot XOR swizzle (slot ^= row&7).
// wave w owns q-rows w*16..+15; lane l: lq=l&15, lg=l>>4.
// QK^T: A=Q rows, B=K rows. PV: A=P rows, B=V^T rows (vt staged global).
// scores C/D map: row = w16 + lg*4 + q, col = n*16 + lq.
// ---------------------------------------------------------------
__device__ __forceinline__ int swz64(int r, int c) {
    return (r << 6) + ((((c >> 3) ^ (r & 7))) << 3) + (c & 7);
}

__device__ __forceinline__ void stg_load(const ushort* __restrict__ g, int gstride,
                                         int tid, short8& va, short8& vb) {
    int s1 = tid + 256;
    va = *(const short8*)&g[(size_t)(tid >> 3)*gstride + ((tid & 7) << 3)];
    vb = *(const short8*)&g[(size_t)(s1  >> 3)*gstride + ((s1  & 7) << 3)];
}

__device__ __forceinline__ void stg_write(ushort* lds, int tid, short8 va, short8 vb) {
    int s1 = tid + 256;
    *(short8*)&lds[swz64(tid >> 3, (tid & 7) << 3)] = va;
    *(short8*)&lds[swz64(s1  >> 3, (s1  & 7) << 3)] = vb;
}

__global__ __launch_bounds__(256) void attn_mfma_kernel(
    const ushort* __restrict__ qkb, const ushort* __restrict__ vtb,
    const float* __restrict__ sp,
    ushort* __restrict__ obuf, float* __restrict__ de_acc, float* __restrict__ fe_acc)
{
    __shared__ ushort Qs[64*64];
    __shared__ ushort Ks[2][64*64];
    __shared__ ushort Vts[2][64*64];
    __shared__ ushort Ps[64*64];
    __shared__ float sps[2][64][4];

    int tile = blockIdx.x & 15;
    int h = (blockIdx.x >> 4) % H_;
    int b = blockIdx.x / (16 * H_);
    int i0 = tile * 64;

    int tid = threadIdx.x, w = tid >> 6, l = tid & 63;
    int lq = l & 15, lg = l >> 4;
    int w16 = w * 16;

    const ushort* kbase = qkb + 768 + h*64;
    const ushort* vbase = vtb + (size_t)((b*H_ + h)*DH_)*S_;

    // prologue: stage Q + tile 0 of K/V/sps (visible after first loop barrier)
    {
        short8 qa, qb2;
        stg_load(qkb + (size_t)(b*S_ + i0)*1536 + h*64, 1536, tid, qa, qb2);
        stg_write(Qs, tid, qa, qb2);
        short8 ka, kb2, va, vb2;
        stg_load(kbase + (size_t)(b*S_)*1536, 1536, tid, ka, kb2);
        stg_load(vbase, S_, tid, va, vb2);
        stg_write(Ks[0], tid, ka, kb2);
        stg_write(Vts[0], tid, va, vb2);
        if (tid < 64) {
            sps[0][tid][0] = sp[(b*S_+tid)*3+0];
            sps[0][tid][1] = sp[(b*S_+tid)*3+1];
            sps[0][tid][2] = sp[(b*S_+tid)*3+2];
        }
    }

    // per-lane q-row info
    float sq0[4], sq1[4], sq2[4];
    #pragma unroll
    for (int q = 0; q < 4; ++q) {
        int i = i0 + w16 + lg*4 + q;
        sq0[q] = sp[(b*S_+i)*3+0];
        sq1[q] = sp[(b*S_+i)*3+1];
        sq2[q] = sp[(b*S_+i)*3+2];
    }

    float M[4], Zp[4], Sdep[4], Swsp[4];    // M replicated; Zp/Sdep/Swsp per-lane partials
    f32x4 O[4];
    #pragma unroll
    for (int q = 0; q < 4; ++q) { M[q] = -1e30f; Zp[q] = 0.f; Sdep[q] = 0.f; Swsp[q] = 0.f; }
    #pragma unroll
    for (int n = 0; n < 4; ++n) { O[n][0]=0.f; O[n][1]=0.f; O[n][2]=0.f; O[n][3]=0.f; }

    int cur = 0;
    for (int j0 = 0; j0 <= i0; j0 += 64, cur ^= 1) {
        __syncthreads();   // stage for buf[cur] visible; prior reads of buf[cur^1] done

        // ---- issue next tile's loads early (latency hides under compute) ----
        bool haveNext = (j0 + 64 <= i0);
        short8 nka, nkb, nva, nvb;
        float ns0 = 0.f, ns1 = 0.f, ns2 = 0.f;
        if (haveNext) {
            stg_load(kbase + (size_t)(b*S_ + j0 + 64)*1536, 1536, tid, nka, nkb);
            stg_load(vbase + j0 + 64, S_, tid, nva, nvb);
            if (tid < 64) {
                ns0 = sp[(b*S_+j0+64+tid)*3+0];
                ns1 = sp[(b*S_+j0+64+tid)*3+1];
                ns2 = sp[(b*S_+j0+64+tid)*3+2];
            }
        }

        // ---- QK^T ----
        f32x4 sacc[4];
        #pragma unroll
        for (int n = 0; n < 4; ++n) { sacc[n][0]=0.f; sacc[n][1]=0.f; sacc[n][2]=0.f; sacc[n][3]=0.f; }
        short8 aq0 = *(const short8*)&Qs[swz64(w16+lq, lg*8)];
        short8 aq1 = *(const short8*)&Qs[swz64(w16+lq, 32+lg*8)];
        #pragma unroll
        for (int n = 0; n < 4; ++n) {
            short8 bk0 = *(const short8*)&Ks[cur][swz64(n*16+lq, lg*8)];
            short8 bk1 = *(const short8*)&Ks[cur][swz64(n*16+lq, 32+lg*8)];
            sacc[n] = __builtin_amdgcn_mfma_f32_16x16x32_bf16(aq0, bk0, sacc[n], 0, 0, 0);
            sacc[n] = __builtin_amdgcn_mfma_f32_16x16x32_bf16(aq1, bk1, sacc[n], 0, 0, 0);
        }

        // ---- penalty (+ mask only on diagonal tile) ----
        float dstv[4][4];
        #pragma unroll
        for (int n = 0; n < 4; ++n) {
            float c0 = sps[cur][n*16+lq][0], c1 = sps[cur][n*16+lq][1], c2 = sps[cur][n*16+lq][2];
            #pragma unroll
            for (int q = 0; q < 4; ++q) {
                float e0 = sq0[q]-c0, e1 = sq1[q]-c1, e2 = sq2[q]-c2;
                float dist = sqrtf(e0*e0 + e1*e1 + e2*e2 + 1e-12f);
                dstv[n][q] = dist;
                sacc[n][q] = sacc[n][q]*0.125f - dist;
            }
        }
        if (j0 == i0) {    // block-uniform branch: causal mask bites only here
            #pragma unroll
            for (int n = 0; n < 4; ++n) {
                int j = j0 + n*16 + lq;
                #pragma unroll
                for (int q = 0; q < 4; ++q)
                    sacc[n][q] = (j <= i0 + w16 + lg*4 + q) ? sacc[n][q] : -1e30f;
            }
        }

        // ---- online max + deferred stats ----
        float ev[4][4];
        #pragma unroll
        for (int q = 0; q < 4; ++q) {
            float mt = fmaxf(fmaxf(sacc[0][q], sacc[1][q]), fmaxf(sacc[2][q], sacc[3][q]));
            mt = fmaxf(mt, __shfl_xor(mt, 1, 64));
            mt = fmaxf(mt, __shfl_xor(mt, 2, 64));
            mt = fmaxf(mt, __shfl_xor(mt, 4, 64));
            mt = fmaxf(mt, __shfl_xor(mt, 8, 64));
            float Mn = fmaxf(M[q], mt);
            float scale = __expf(M[q] - Mn);
            float zl = 0.f, dl = 0.f, wl = 0.f;
            #pragma unroll
            for (int n = 0; n < 4; ++n) {
                float e = __expf(sacc[n][q] - Mn);
                ev[n][q] = e;
                zl += e; dl += e*dstv[n][q]; wl += e*sacc[n][q];
            }
            Zp[q]   = Zp[q]  *scale + zl;
            Sdep[q] = Sdep[q]*scale + dl;
            Swsp[q] = Swsp[q]*scale + wl;
            M[q] = Mn;
            O[0][q] *= scale; O[1][q] *= scale; O[2][q] *= scale; O[3][q] *= scale;
        }

        // ---- P -> LDS (rows are wave-private; no barrier needed) ----
        #pragma unroll
        for (int n = 0; n < 4; ++n)
            #pragma unroll
            for (int q = 0; q < 4; ++q)
                Ps[swz64(w16 + lg*4 + q, n*16 + lq)] = f2bf(ev[n][q]);

        // ---- PV ----
        short8 pa0 = *(const short8*)&Ps[swz64(w16+lq, lg*8)];
        short8 pa1 = *(const short8*)&Ps[swz64(w16+lq, 32+lg*8)];
        #pragma unroll
        for (int n = 0; n < 4; ++n) {
            short8 v0 = *(const short8*)&Vts[cur][swz64(n*16+lq, lg*8)];
            short8 v1 = *(const short8*)&Vts[cur][swz64(n*16+lq, 32+lg*8)];
            O[n] = __builtin_amdgcn_mfma_f32_16x16x32_bf16(pa0, v0, O[n], 0, 0, 0);
            O[n] = __builtin_amdgcn_mfma_f32_16x16x32_bf16(pa1, v1, O[n], 0, 0, 0);
        }

        // ---- write next tile's staged regs to the other buffer ----
        if (haveNext) {
            stg_write(Ks[cur^1], tid, nka, nkb);
            stg_write(Vts[cur^1], tid, nva, nvb);
            if (tid < 64) {
                sps[cur^1][tid][0] = ns0;
                sps[cur^1][tid][1] = ns1;
                sps[cur^1][tid][2] = ns2;
            }
        }
    }

    // ---- final cross-lane reduce of deferred stats (once) ----
    float Z[4], Sde[4], Sws[4];
    #pragma unroll
    for (int q = 0; q < 4; ++q) {
        float z = Zp[q], d = Sdep[q], ws = Swsp[q];
        z += __shfl_xor(z, 1, 64); z += __shfl_xor(z, 2, 64);
        z += __shfl_xor(z, 4, 64); z += __shfl_xor(z, 8, 64);
        d += __shfl_xor(d, 1, 64); d += __shfl_xor(d, 2, 64);
        d += __shfl_xor(d, 4, 64); d += __shfl_xor(d, 8, 64);
        ws += __shfl_xor(ws, 1, 64); ws += __shfl_xor(ws, 2, 64);
        ws += __shfl_xor(ws, 4, 64); ws += __shfl_xor(ws, 8, 64);
        Z[q] = z; Sde[q] = d; Sws[q] = ws;
    }

    // ---- epilogue ----
    #pragma unroll
    for (int q = 0; q < 4; ++q) {
        float invz = 1.0f / Z[q];
        int i = i0 + w16 + lg*4 + q;
        ushort* op = obuf + (size_t)(b*S_ + i)*D_ + h*DH_ + lq;
        op[0]  = f2bf(O[0][q]*invz);
        op[16] = f2bf(O[1][q]*invz);
        op[32] = f2bf(O[2][q]*invz);
        op[48] = f2bf(O[3][q]*invz);
    }

    float dsum = 0.f, fsum = 0.f;
    if (lq == 0) {
        #pragma unroll
        for (int q = 0; q < 4; ++q) {
            dsum += Sde[q] / Z[q];
            fsum += M[q] + __logf(Z[q]) - Sws[q] / Z[q];
        }
    }
    #pragma unroll
    for (int m = 32; m > 0; m >>= 1) {
        dsum += __shfl_xor(dsum, m, 64);
        fsum += __shfl_xor(fsum, m, 64);
    }
    if (l == 0) {
        atomicAdd(de_acc, dsum * (1.0f/49152.0f));
        atomicAdd(fe_acc, fsum * (1.0f/49152.0f));
    }
}

// ---------------------------------------------------------------
__global__ __launch_bounds__(256) void ce_kernel(
    const float* __restrict__ logits, const int* __restrict__ targets,
    float* __restrict__ ce_acc)
{
    __shared__ float red[4];
    int r = blockIdx.x, tid = threadIdx.x;
    float x = logits[(size_t)r*V_ + tid];
    float m = block_max(x, red);
    float e = __expf(x - m);
    float s = block_sum(e, red);
    if (tid == 0) {
        float lse = m + __logf(s);
        float tl = logits[(size_t)r*V_ + targets[r]];
        atomicAdd(ce_acc, (lse - tl) * (1.0f/(float)BS_));
    }
}

__global__ __launch_bounds__(256) void rep_kernel(
    const float* __restrict__ tp, float* __restrict__ rep_acc)
{
    __shared__ float red[4];
    int i = blockIdx.x, j = threadIdx.x;
    float val = 0.0f;
    if (i != j) {
        float d0 = tp[i*3+0]-tp[j*3+0];
        float d1 = tp[i*3+1]-tp[j*3+1];
        float d2 = tp[i*3+2]-tp[j*3+2];
        float dm = sqrtf(d0*d0 + d1*d1 + d2*d2 + 1e-12f);
        val = 1.0f/(dm + 1e-4f);
    }
    float s = block_sum(val, red);
    if (j == 0) atomicAdd(rep_acc, s);
}

__global__ void finalize_kernel(float* __restrict__ out4, const float* __restrict__ acc) {
    if (threadIdx.x == 0) {
        float de = acc[0], fe = acc[1];
        float rep = acc[2] * (1.0f/(256.0f*255.0f));
        float ce = acc[3];
        out4[0] = ce + 0.01f*de + 0.01f*fe + 0.01f*rep;
        out4[1] = de;
        out4[2] = fe;
        out4[3] = rep;
    }
}

// ---------------------------------------------------------------
extern "C" void kernel_launch(void* const* d_in, const int* in_sizes, int n_in,
                              void* d_out, int out_size, void* d_ws, size_t ws_size,
                              hipStream_t stream)
{
    const int*   idx      = (const int*)  d_in[0];
    const int*   targets  = (const int*)  d_in[1];
    const float* tok_emb  = (const float*)d_in[2];
    const float* pos_emb  = (const float*)d_in[3];
    const float* tok_pos  = (const float*)d_in[4];
    const float* pproj    = (const float*)d_in[5];
    const float* ln1_g    = (const float*)d_in[6];
    const float* ln1_b    = (const float*)d_in[7];
    const float* Wqkv     = (const float*)d_in[8];
    const float* Wproj    = (const float*)d_in[9];
    const float* ln2_g    = (const float*)d_in[10];
    const float* ln2_b    = (const float*)d_in[11];
    const float* Wff1     = (const float*)d_in[12];
    const float* bff1     = (const float*)d_in[13];
    const float* Wff2     = (const float*)d_in[14];
    const float* bff2     = (const float*)d_in[15];
    const float* lnf_g    = (const float*)d_in[16];
    const float* lnf_b    = (const float*)d_in[17];

    float* out = (float*)d_out;

    // workspace layout
    float* wsf  = (float*)d_ws;
    float* acc  = wsf;                                  // 8
    float* sp   = wsf + 8;                              // 12288
    float* x    = sp + 12288;                           // BS_*D_ f32
    float* hf   = x + (size_t)BS_*D_;                   // BS_*D_ f32 (lnf out)
    ushort* hbf  = (ushort*)(hf + (size_t)BS_*D_);      // BS_*D_ bf16
    ushort* ffbf = hbf + (size_t)BS_*D_;                // BS_*D4_ bf16
    ushort* qkb  = ffbf + (size_t)BS_*D4_;              // BS_*1536 bf16 (q,k)
    ushort* vtb  = qkb + (size_t)BS_*1536;              // 3072*1024 bf16 (v^T)
    ushort* wqT  = vtb + (size_t)3072*1024;             // D3_*D_
    ushort* wpT  = wqT + (size_t)D3_*D_;                // D_*D_
    ushort* w1T  = wpT + (size_t)D_*D_;                 // D4_*D_
    ushort* w2T  = w1T + (size_t)D4_*D_;                // D_*D4_

    zero_kernel<<<1, 64, 0, stream>>>(acc);
    embed_kernel<<<BS_, 256, 0, stream>>>(idx, tok_emb, pos_emb, tok_pos, pproj, x, sp);

    for (int l = 0; l < L_; ++l) {
        transpose_all_kernel<<<6912, 256, 0, stream>>>(
            Wqkv + (size_t)l*D_*D3_, Wproj + (size_t)l*D_*D_,
            Wff1 + (size_t)l*D_*D4_, Wff2 + (size_t)l*D4_*D_,
            wqT, wpT, w1T, w2T);

        ln_kernel<1><<<BS_, 256, 0, stream>>>(x, ln1_g + l*D_, ln1_b + l*D_, hbf);

        gemm_bf16_kernel<4><<<dim3(D3_/128, BS_/128), 256, 0, stream>>>(
            hbf, wqT, nullptr, nullptr, qkb, vtb, BS_, D3_, D_);

        attn_mfma_kernel<<<B_*H_*(S_/64), 256, 0, stream>>>(qkb, vtb, sp, hbf, &acc[0], &acc[1]);

        gemm_bf16_kernel<1><<<dim3(D_/128, BS_/128), 256, 0, stream>>>(
            hbf, wpT, nullptr, x, x, nullptr, BS_, D_, D_);

        ln_kernel<1><<<BS_, 256, 0, stream>>>(x, ln2_g + l*D_, ln2_b + l*D_, hbf);

        gemm_bf16_kernel<2><<<dim3(D4_/128, BS_/128), 256, 0, stream>>>(
            hbf, w1T, bff1 + (size_t)l*D4_, nullptr, ffbf, nullptr, BS_, D4_, D_);

        gemm_bf16_kernel<3><<<dim3(D_/128, BS_/128), 256, 0, stream>>>(
            ffbf, w2T, bff2 + (size_t)l*D_, x, x, nullptr, BS_, D_, D4_);
    }

    ln_kernel<0><<<BS_, 256, 0, stream>>>(x, lnf_g, lnf_b, hf);

    // tied lm_head in f32 for logit accuracy
    gemm_kernel<0,true><<<dim3(V_/64, BS_/64), 256, 0, stream>>>(
        hf, tok_emb, nullptr, nullptr, out, BS_, V_, D_);

    ce_kernel<<<BS_, 256, 0, stream>>>(out, targets, &acc[3]);
    rep_kernel<<<V_, 256, 0, stream>>>(tok_pos, &acc[2]);
    finalize_kernel<<<1, 64, 0, stream>>>(out + BSV_, acc);
}